// Round 11
// baseline (163.148 us; speedup 1.0000x reference)
//
#include <hip/hip_runtime.h>
#include <hip/hip_bf16.h>

// MoE MLP: x[1,2048,768] fp32, router_w[16,768], w1[768,12288], w2[12288,768]
// out[1,2048,768] fp32.  Experts: 8x512 + 8x1024, top-8, normalized.
// Dense bf16 GEMMs (reference is dense+masked); comb folded into H.
// GEMM core: 256x128 tile, BK=32, 512 thr, 2 BLOCKS/CU (48KB LDS dbuf,
// ~110 VGPR via acc[8][2]). R8-proven counted-vmcnt 2-phase gating:
// per tile 3 staging loads [B, A0 | A1]; ph0 vmcnt(1), ph1 vmcnt(2);
// A chunks row-bit6-interleaved so ph0 (m0-3) reads chunk0 for BOTH wr.
// XOR-swizzled LDS (64B rows), XCD-ownership map (gemm1), affine pointers.

#define T_TOK 2048
#define D_EMB 768
#define W_TOT 12288
#define N_EXP 16

typedef __attribute__((ext_vector_type(4))) float f32x4;
typedef __attribute__((ext_vector_type(8))) short bf16x8;

typedef __attribute__((address_space(1))) const unsigned int as1c_u32;
typedef __attribute__((address_space(3))) unsigned int as3_u32;

__device__ __forceinline__ void gload16(const void* g, void* l) {
  __builtin_amdgcn_global_load_lds((as1c_u32*)g, (as3_u32*)l, 16, 0, 0);
}

__device__ __forceinline__ unsigned short f2bf(float f) {
  __hip_bfloat16 h = __float2bfloat16(f);
  return *reinterpret_cast<unsigned short*>(&h);
}

__device__ __forceinline__ float gelu_f(float x) {
  // jax.nn.gelu default (approximate=True, tanh form)
  float x3 = x * x * x;
  float a = 0.7978845608028654f * __builtin_fmaf(0.044715f, x3, x);
  a = fminf(fmaxf(a, -20.f), 20.f);
  float e = __expf(-2.0f * a);
  float t = (1.0f - e) / (1.0f + e);
  return 0.5f * x * (1.0f + t);
}

// in fp32 [R][C] -> out bf16 [C][R]
__global__ __launch_bounds__(256) void transpose_cvt_kernel(
    const float* __restrict__ in, unsigned short* __restrict__ out, int R, int C) {
  __shared__ float tile[32][33];
  int c0 = blockIdx.x * 32;
  int r0 = blockIdx.y * 32;
  int i = threadIdx.x;
  {
    int r = i >> 3, c4 = (i & 7) * 4;
    float4 v = *(const float4*)(in + (size_t)(r0 + r) * C + c0 + c4);
    tile[r][c4 + 0] = v.x; tile[r][c4 + 1] = v.y;
    tile[r][c4 + 2] = v.z; tile[r][c4 + 3] = v.w;
  }
  __syncthreads();
  {
    int c = i >> 3, r4 = (i & 7) * 4;
    ushort4 o;
    o.x = f2bf(tile[r4 + 0][c]);
    o.y = f2bf(tile[r4 + 1][c]);
    o.z = f2bf(tile[r4 + 2][c]);
    o.w = f2bf(tile[r4 + 3][c]);
    *(ushort4*)(out + (size_t)(c0 + c) * R + r0 + r4) = o;
  }
}

// ---------------- router (also emits xb = bf16(x)) ----------------

__global__ __launch_bounds__(256) void router_kernel(
    const float* __restrict__ x, const float* __restrict__ rw,
    float* __restrict__ comb, unsigned short* __restrict__ xbout) {
  int tid = threadIdx.x, lane = tid & 63, w = tid >> 6;
  int t = blockIdx.x * 4 + w;
  const float* xr = x + (size_t)t * D_EMB;
  float xv[12];
#pragma unroll
  for (int i = 0; i < 12; ++i) xv[i] = xr[lane + 64 * i];
#pragma unroll
  for (int i = 0; i < 12; ++i)
    xbout[(size_t)t * D_EMB + lane + 64 * i] = f2bf(xv[i]);
  float lg[16];
#pragma unroll
  for (int e = 0; e < 16; ++e) {
    const float* we = rw + (size_t)e * D_EMB;
    float p = 0.f;
#pragma unroll
    for (int i = 0; i < 12; ++i) p = __builtin_fmaf(xv[i], we[lane + 64 * i], p);
#pragma unroll
    for (int off = 32; off >= 1; off >>= 1) p += __shfl_xor(p, off, 64);
    lg[e] = p;
  }
  float mx = lg[0];
#pragma unroll
  for (int e = 1; e < 16; ++e) mx = fmaxf(mx, lg[e]);
  float ex[16];
#pragma unroll
  for (int e = 0; e < 16; ++e) ex[e] = __expf(lg[e] - mx);
  float selsum = 0.f, myval = 0.f;
#pragma unroll
  for (int e = 0; e < 16; ++e) {
    int rank = 0;
#pragma unroll
    for (int e2 = 0; e2 < 16; ++e2)
      rank += (ex[e2] > ex[e]) || (ex[e2] == ex[e] && e2 < e);
    bool sel = rank < 8;
    float v = sel ? ex[e] : 0.f;
    selsum += v;
    if (e == lane) myval = v;
  }
  if (lane < 16) comb[(size_t)t * N_EXP + lane] = myval / selsum;
}

// ---------- 8-wave 2-block/CU counted-vmcnt GEMM, 256x128, BK=32 ----------
// A row-major [M][LD], B N-major [N][LD] (bf16, K contiguous).
// 8 waves = 2(M) x 4(N); per-wave 128x32 out; acc[8][2] (64 f32).
// LDS 48KB: A dbuf 2x16KB @0 (each = 2 row-interleaved 8KB chunks:
// chunk j holds rows with bit6==j), B dbuf 2x8KB @32768.
// Per tile: issue [B, A0 | A1]; ph0 gate vmcnt(1) (B,A0 landed), ph1 gate
// vmcnt(2) (A1 landed); loads issued in tile t consumed in t+1. 2 barriers.
// MAP: 0 = gemm1 XCD-owns-12-N-panels (grid 768), 1 = gemm2 generic split-K.
// EPI: 1 = gelu*comb -> bf16 H, 0 = fp32 partial.

template <int EPI, int MAP, int LD>
__global__ __launch_bounds__(512, 4) void gemm_kernel(
    const unsigned short* __restrict__ Ag, const unsigned short* __restrict__ Bg,
    int ntiles, int kchunk, int splits,
    const float* __restrict__ comb, unsigned short* __restrict__ hout,
    float* __restrict__ pout) {
  __shared__ __align__(16) char smem[49152];

  const int tid = threadIdx.x;
  const int lane = tid & 63;
  const int wid = tid >> 6;
  const int wr = wid >> 2;        // 0..1  (M half: 128 rows)
  const int wc = wid & 3;         // 0..3  (N quarter: 32 cols)

  int mt, nt, zt;
  {
    int bid = blockIdx.x;
    if (MAP == 0) {               // gemm1: XCD owns 12 N-panels, M fastest
      int xcd = bid & 7, r = bid >> 3;        // r in 0..95
      nt = xcd * 12 + (r >> 3); mt = r & 7; zt = 0;
    } else {                      // gemm2: generic split-K decode
      zt = bid % splits; int rr = bid / splits;
      nt = rr % 6; mt = rr / 6;
    }
  }
  const int rm0 = mt * 256;
  const int cn0 = nt * 128;
  const int kbeg = zt * kchunk;

  // ---- affine staging pointers (pre-swizzled source, rule #21) ----
  // thread tid covers LDS bytes tid*16 of each 8KB chunk: subrow s=tid>>2,
  // 16B-slot tid&3; source col slot = (tid&3) ^ (s&3) (matches read swizzle).
  const int s = tid >> 2;
  const int scol = ((tid & 3) ^ (s & 3)) << 4;
  const int rA = (s & 63) + ((s >> 6) << 7);   // chunk0 rows (bit6==0)
  const char* pA0 = (const char*)Ag + ((size_t)(rm0 + rA) * LD + kbeg) * 2 + scol;
  const char* pA1 = pA0 + (size_t)64 * LD * 2; // chunk1 = +64 rows
  const char* pB  = (const char*)Bg + ((size_t)(cn0 + s) * LD + kbeg) * 2 + scol;

  // ---- LDS read bases: 64B rows, slot = (lane>>4) ^ (lane&3) ----
  const int slot = ((lane >> 4) ^ (lane & 3)) << 4;
  const int abase = wr * 4096 + (lane & 15) * 64 + slot;            // +aoff +p*8192 +mi*1024
  const int bbase = 32768 + (wc * 32 + (lane & 15)) * 64 + slot;    // +boff +n*1024

  f32x4 acc[8][2];
#pragma unroll
  for (int m = 0; m < 8; ++m)
#pragma unroll
    for (int n = 0; n < 2; ++n) acc[m][n] = (f32x4){0.f, 0.f, 0.f, 0.f};

  // prologue: tile 0, steady-state issue order [B, A0, A1]
  gload16(pB, smem + 32768 + wid * 1024);
  gload16(pA0, smem + wid * 1024);
  gload16(pA1, smem + 8192 + wid * 1024);
  pB += 64; pA0 += 64; pA1 += 64;
  __builtin_amdgcn_sched_barrier(0);

  int aoff = 0, boff = 0;
  bf16x8 a[4], b[2];
  for (int t = 0; t < ntiles; ++t) {
    const int nA = aoff ^ 16384;
    const int nB = boff ^ 8192;

    // ---- phase 0: m0-3 (A chunk0) x both n ----
    asm volatile("s_waitcnt vmcnt(1)" ::: "memory");  // B,A0 of cur landed
    __builtin_amdgcn_s_barrier();
    __builtin_amdgcn_sched_barrier(0);
#pragma unroll
    for (int m = 0; m < 4; ++m)
      a[m] = *(const bf16x8*)(smem + aoff + abase + m * 1024);
    b[0] = *(const bf16x8*)(smem + boff + bbase);
    b[1] = *(const bf16x8*)(smem + boff + bbase + 1024);
    gload16(pB, smem + 32768 + nB + wid * 1024);   // stage tile t+1
    gload16(pA0, smem + nA + wid * 1024);
    __builtin_amdgcn_sched_barrier(0);
    __builtin_amdgcn_s_setprio(1);
#pragma unroll
    for (int m = 0; m < 4; ++m) {
      acc[m][0] = __builtin_amdgcn_mfma_f32_16x16x32_bf16(a[m], b[0], acc[m][0], 0, 0, 0);
      acc[m][1] = __builtin_amdgcn_mfma_f32_16x16x32_bf16(a[m], b[1], acc[m][1], 0, 0, 0);
    }
    __builtin_amdgcn_s_setprio(0);

    // ---- phase 1: m4-7 (A chunk1) x both n ----
    asm volatile("s_waitcnt vmcnt(2)" ::: "memory");  // A1 of cur landed
    __builtin_amdgcn_s_barrier();
    __builtin_amdgcn_sched_barrier(0);
#pragma unroll
    for (int m = 0; m < 4; ++m)
      a[m] = *(const bf16x8*)(smem + aoff + 8192 + abase + m * 1024);
    gload16(pA1, smem + nA + 8192 + wid * 1024);
    pB += 64; pA0 += 64; pA1 += 64;
    __builtin_amdgcn_sched_barrier(0);
    __builtin_amdgcn_s_setprio(1);
#pragma unroll
    for (int m = 0; m < 4; ++m) {
      acc[4 + m][0] = __builtin_amdgcn_mfma_f32_16x16x32_bf16(a[m], b[0], acc[4 + m][0], 0, 0, 0);
      acc[4 + m][1] = __builtin_amdgcn_mfma_f32_16x16x32_bf16(a[m], b[1], acc[4 + m][1], 0, 0, 0);
    }
    __builtin_amdgcn_s_setprio(0);

    aoff = nA; boff = nB;
  }

  asm volatile("s_waitcnt vmcnt(0)" ::: "memory");  // drain tail stages
  __syncthreads();

  // ---- epilogue ----
  const int r0 = (lane >> 4) * 4;
  const int cl = lane & 15;
  if constexpr (EPI == 1) {
    float* Cwf = (float*)smem;   // reuse staging LDS: [256 rows][16 experts]
    {
      int row = tid >> 1, c8 = (tid & 1) * 8;
      const float* sc = comb + (size_t)(rm0 + row) * N_EXP + c8;
      *(float4*)&Cwf[row * 16 + c8] = *(const float4*)sc;
      *(float4*)&Cwf[row * 16 + c8 + 4] = *(const float4*)(sc + 4);
    }
    __syncthreads();
#pragma unroll
    for (int n = 0; n < 2; ++n) {
      int colg = cn0 + wc * 32 + n * 16 + cl;
      int e = (colg < 4096) ? (colg >> 9) : (8 + ((colg - 4096) >> 10));
#pragma unroll
      for (int m = 0; m < 8; ++m) {
        int rl = wr * 128 + m * 16 + r0;
#pragma unroll
        for (int r = 0; r < 4; ++r) {
          float v = gelu_f(acc[m][n][r]) * Cwf[(rl + r) * 16 + e];
          hout[(size_t)(rm0 + rl + r) * W_TOT + colg] = f2bf(v);
        }
      }
    }
  } else {
    float* pz = pout + (size_t)zt * T_TOK * D_EMB;
#pragma unroll
    for (int n = 0; n < 2; ++n) {
      int colg = cn0 + wc * 32 + n * 16 + cl;
#pragma unroll
      for (int m = 0; m < 8; ++m) {
        int rl = wr * 128 + m * 16 + r0;
#pragma unroll
        for (int r = 0; r < 4; ++r)
          pz[(size_t)(rm0 + rl + r) * D_EMB + colg] = acc[m][n][r];
      }
    }
  }
}

__global__ __launch_bounds__(256) void reduce_kernel(
    const float* __restrict__ partial, float* __restrict__ out, int splits) {
  int i = (blockIdx.x * 256 + threadIdx.x) * 4;
  if (i >= T_TOK * D_EMB) return;
  float4 sv = *(const float4*)(partial + i);
  for (int sp = 1; sp < splits; ++sp) {
    float4 v = *(const float4*)(partial + (size_t)sp * T_TOK * D_EMB + i);
    sv.x += v.x; sv.y += v.y; sv.z += v.z; sv.w += v.w;
  }
  *(float4*)(out + i) = sv;
}

// ---------------- launcher ----------------

extern "C" void kernel_launch(void* const* d_in, const int* in_sizes, int n_in,
                              void* d_out, int out_size, void* d_ws, size_t ws_size,
                              hipStream_t stream) {
  const float* x = (const float*)d_in[0];
  const float* router_w = (const float*)d_in[1];
  const float* w1 = (const float*)d_in[2];
  const float* w2 = (const float*)d_in[3];
  float* out = (float*)d_out;

  char* ws = (char*)d_ws;
  size_t off = 0;
  auto alloc = [&](size_t bytes) {
    char* p = ws + off;
    off += (bytes + 255) & ~(size_t)255;
    return p;
  };
  unsigned short* xb  = (unsigned short*)alloc((size_t)T_TOK * D_EMB * 2);
  unsigned short* w1t = (unsigned short*)alloc((size_t)W_TOT * D_EMB * 2);
  unsigned short* w2t = (unsigned short*)alloc((size_t)D_EMB * W_TOT * 2);
  unsigned short* h   = (unsigned short*)alloc((size_t)T_TOK * W_TOT * 2);
  float* comb         = (float*)alloc((size_t)T_TOK * N_EXP * 4);

  // split-K for GEMM2: prefer 16 (grid 768, balanced 3 blocks/CU)
  int splits = 16;
  if (off + (size_t)16 * T_TOK * D_EMB * 4 > ws_size) splits = 8;
  if (off + (size_t)8 * T_TOK * D_EMB * 4 > ws_size) splits = 4;
  float* partial = (float*)alloc((size_t)splits * T_TOK * D_EMB * 4);
  int kchunk = W_TOT / splits;

  transpose_cvt_kernel<<<dim3(W_TOT / 32, D_EMB / 32), 256, 0, stream>>>(w1, w1t, D_EMB, W_TOT);
  transpose_cvt_kernel<<<dim3(D_EMB / 32, W_TOT / 32), 256, 0, stream>>>(w2, w2t, W_TOT, D_EMB);
  router_kernel<<<T_TOK / 4, 256, 0, stream>>>(x, router_w, comb, xb);

  // GEMM1: H = gelu(X W1) * comb ; grid 768 = 8 XCD x (12 N x 8 M); 24 tiles
  gemm_kernel<1, 0, D_EMB><<<768, 512, 0, stream>>>(
      xb, w1t, D_EMB / 32, D_EMB, 1, comb, h, nullptr);

  // GEMM2: OUT = H W2 ; grid 48*splits (6 N x 8 M per split)
  gemm_kernel<0, 1, W_TOT><<<48 * splits, 512, 0, stream>>>(
      h, w2t, kchunk / 32, kchunk, splits, nullptr, nullptr, partial);

  reduce_kernel<<<(T_TOK * D_EMB) / 1024, 256, 0, stream>>>(partial, out, splits);
}

// Round 12
// 158.024 us; speedup vs baseline: 1.0324x; 1.0324x over previous
//
#include <hip/hip_runtime.h>
#include <hip/hip_bf16.h>

// MoE MLP: x[1,2048,768] fp32, router_w[16,768], w1[768,12288], w2[12288,768]
// out[1,2048,768] fp32.  Experts: 8x512 + 8x1024, top-8, normalized.
// Dense bf16 GEMMs (reference is dense+masked); comb folded into H.
// GEMM core: R8-proven 256x192 / BK=64 / 8-wave / counted-vmcnt 2-phase
// pipeline, UNCHANGED. This round changes only the block->XCD mapping so
// each XCD's working set is L2-resident (the measured wall is ~6.5 TB/s of
// L3-served staging traffic):
//  - gemm1: XCD = M-tile (mt = bid&7): 32 concurrent blocks/XCD share ONE
//    384KB A-panel (L2-hot); B streams read-once. L3 reads 352 -> ~148 MB.
//  - gemm2: splits=16, XCD owns split-pair {xcd, xcd+8}: per-phase set =
//    A-chunk 3MB + B-chunk 1.1MB ~ L2-fit; grid 512 = exact 2 rounds.

#define T_TOK 2048
#define D_EMB 768
#define W_TOT 12288
#define N_EXP 16

typedef __attribute__((ext_vector_type(4))) float f32x4;
typedef __attribute__((ext_vector_type(8))) short bf16x8;

typedef __attribute__((address_space(1))) const unsigned int as1c_u32;
typedef __attribute__((address_space(3))) unsigned int as3_u32;

__device__ __forceinline__ void gload16(const void* g, void* l) {
  __builtin_amdgcn_global_load_lds((as1c_u32*)g, (as3_u32*)l, 16, 0, 0);
}

__device__ __forceinline__ unsigned short f2bf(float f) {
  __hip_bfloat16 h = __float2bfloat16(f);
  return *reinterpret_cast<unsigned short*>(&h);
}

__device__ __forceinline__ float gelu_f(float x) {
  // jax.nn.gelu default (approximate=True, tanh form)
  float x3 = x * x * x;
  float a = 0.7978845608028654f * __builtin_fmaf(0.044715f, x3, x);
  a = fminf(fmaxf(a, -20.f), 20.f);
  float e = __expf(-2.0f * a);
  float t = (1.0f - e) / (1.0f + e);
  return 0.5f * x * (1.0f + t);
}

// in fp32 [R][C] -> out bf16 [C][R]
__global__ __launch_bounds__(256) void transpose_cvt_kernel(
    const float* __restrict__ in, unsigned short* __restrict__ out, int R, int C) {
  __shared__ float tile[32][33];
  int c0 = blockIdx.x * 32;
  int r0 = blockIdx.y * 32;
  int i = threadIdx.x;
  {
    int r = i >> 3, c4 = (i & 7) * 4;
    float4 v = *(const float4*)(in + (size_t)(r0 + r) * C + c0 + c4);
    tile[r][c4 + 0] = v.x; tile[r][c4 + 1] = v.y;
    tile[r][c4 + 2] = v.z; tile[r][c4 + 3] = v.w;
  }
  __syncthreads();
  {
    int c = i >> 3, r4 = (i & 7) * 4;
    ushort4 o;
    o.x = f2bf(tile[r4 + 0][c]);
    o.y = f2bf(tile[r4 + 1][c]);
    o.z = f2bf(tile[r4 + 2][c]);
    o.w = f2bf(tile[r4 + 3][c]);
    *(ushort4*)(out + (size_t)(c0 + c) * R + r0 + r4) = o;
  }
}

// ---------------- router (also emits xb = bf16(x)) ----------------

__global__ __launch_bounds__(256) void router_kernel(
    const float* __restrict__ x, const float* __restrict__ rw,
    float* __restrict__ comb, unsigned short* __restrict__ xbout) {
  int tid = threadIdx.x, lane = tid & 63, w = tid >> 6;
  int t = blockIdx.x * 4 + w;
  const float* xr = x + (size_t)t * D_EMB;
  float xv[12];
#pragma unroll
  for (int i = 0; i < 12; ++i) xv[i] = xr[lane + 64 * i];
#pragma unroll
  for (int i = 0; i < 12; ++i)
    xbout[(size_t)t * D_EMB + lane + 64 * i] = f2bf(xv[i]);
  float lg[16];
#pragma unroll
  for (int e = 0; e < 16; ++e) {
    const float* we = rw + (size_t)e * D_EMB;
    float p = 0.f;
#pragma unroll
    for (int i = 0; i < 12; ++i) p = __builtin_fmaf(xv[i], we[lane + 64 * i], p);
#pragma unroll
    for (int off = 32; off >= 1; off >>= 1) p += __shfl_xor(p, off, 64);
    lg[e] = p;
  }
  float mx = lg[0];
#pragma unroll
  for (int e = 1; e < 16; ++e) mx = fmaxf(mx, lg[e]);
  float ex[16];
#pragma unroll
  for (int e = 0; e < 16; ++e) ex[e] = __expf(lg[e] - mx);
  float selsum = 0.f, myval = 0.f;
#pragma unroll
  for (int e = 0; e < 16; ++e) {
    int rank = 0;
#pragma unroll
    for (int e2 = 0; e2 < 16; ++e2)
      rank += (ex[e2] > ex[e]) || (ex[e2] == ex[e] && e2 < e);
    bool sel = rank < 8;
    float v = sel ? ex[e] : 0.f;
    selsum += v;
    if (e == lane) myval = v;
  }
  if (lane < 16) comb[(size_t)t * N_EXP + lane] = myval / selsum;
}

// ------------- 8-wave counted-vmcnt pipelined GEMM, 256x192 -------------
// Per K-tile: 7 loads in order [B0,B1,B2,A0,A2 | A1,A3]; phase0 waits
// vmcnt(2) (B*,A0,A2 of cur landed), phase1 waits vmcnt(5) (A1,A3 landed).
// Loads issued in tile t are consumed in tile t+1 (never drain to 0).
// MAP: 0 = gemm1 XCD=M-tile (grid 512: mt=bid&7, nt=bid>>3).
//      1 = gemm2 XCD=split-pair (grid 256/512: zt=(bid&7)+8*(r>>5)).
//      2 = generic split-K decode via zsplit.
// EPI: 1 = gelu*comb -> bf16 H, 0 = fp32 partial.

template <int EPI, int MAP>
__global__ __launch_bounds__(512, 2) void gemm_kernel(
    const unsigned short* __restrict__ Ag, const unsigned short* __restrict__ Bg,
    int lda, int ldb, int ntiles, int kchunk, int zsplit,
    const float* __restrict__ comb, unsigned short* __restrict__ hout,
    float* __restrict__ pout) {
  __shared__ __align__(16) char smem[114688];  // A 2x32KB | B 2x24KB

  const int tid = threadIdx.x;
  const int lane = tid & 63;
  const int wid = tid >> 6;
  const int wr = wid >> 2;        // 0..1  (M half: 128 rows)
  const int wc = wid & 3;         // 0..3  (N quarter: 48 cols)

  int mt, nt, zt;
  {
    int bid = blockIdx.x;
    if (MAP == 0) {               // gemm1: XCD = M-tile; N sequential in XCD
      mt = bid & 7; nt = bid >> 3; zt = 0;
    } else if (MAP == 1) {        // gemm2: XCD owns split-pair {x, x+8}
      int xcd = bid & 7, r = bid >> 3;
      zt = xcd + ((r >> 5) << 3);
      int rr = r & 31;
      nt = rr & 3; mt = rr >> 2;
    } else {                      // generic split-K
      zt = bid % zsplit; int rr = bid / zsplit;
      nt = rr & 3; mt = rr >> 2;
    }
  }
  const int rm0 = mt * 256;
  const int cn0 = nt * 192;
  const int kbeg = zt * kchunk;

  // ---- affine staging pointers at tile 0 (pre-swizzled source, rule #21) ----
  auto gsrc = [&](const unsigned short* base, int ld, int row0, int j) {
    int off = j * 8192 + tid * 16;
    int row = off >> 7, inrow = off & 127;
    int scol = inrow ^ ((row & 7) << 4);
    return (const char*)base + ((size_t)(row0 + row) * ld + kbeg) * 2 + scol;
  };
  const char* pA0 = gsrc(Ag, lda, rm0, 0);
  const char* pA1 = gsrc(Ag, lda, rm0, 1);
  const char* pA2 = gsrc(Ag, lda, rm0, 2);
  const char* pA3 = gsrc(Ag, lda, rm0, 3);
  const char* pB0 = gsrc(Bg, ldb, cn0, 0);
  const char* pB1 = gsrc(Bg, ldb, cn0, 1);
  const char* pB2 = gsrc(Bg, ldb, cn0, 2);

  // ---- precomputed LDS read base offsets (bytes, buffer 0) ----
  const int lswz = (lane & 7) << 4;
  const int colk0 = (((lane >> 4) & 3) * 16) ^ lswz;
  const int colk1 = (64 + ((lane >> 4) & 3) * 16) ^ lswz;
  const int abase0 = wr * 16384 + (lane & 15) * 128 + colk0;
  const int abase1 = wr * 16384 + (lane & 15) * 128 + colk1;
  const int bb0 = wc * 6144 + (lane & 15) * 128 + colk0;
  const int bb1 = wc * 6144 + (lane & 15) * 128 + colk1;

  f32x4 acc[8][3];
#pragma unroll
  for (int m = 0; m < 8; ++m)
#pragma unroll
    for (int n = 0; n < 3; ++n) acc[m][n] = (f32x4){0.f, 0.f, 0.f, 0.f};

  // prologue: stage tile 0 into buf 0 (same issue order as steady state)
  gload16(pB0, smem + 65536 + wid * 1024);
  gload16(pB1, smem + 65536 + 8192 + wid * 1024);
  gload16(pB2, smem + 65536 + 16384 + wid * 1024);
  gload16(pA0, smem + wid * 1024);
  gload16(pA2, smem + 16384 + wid * 1024);
  gload16(pA1, smem + 8192 + wid * 1024);
  gload16(pA3, smem + 24576 + wid * 1024);
  pA0 += 128; pA1 += 128; pA2 += 128; pA3 += 128;
  pB0 += 128; pB1 += 128; pB2 += 128;
  __builtin_amdgcn_sched_barrier(0);

  int aoff = 0, boff = 0;
  bf16x8 af[4], ag[4], bfr[3], bgr[3];
  for (int t = 0; t < ntiles; ++t) {
    const int adst = aoff ^ 32768;
    const int bdst = boff ^ 24576;

    // ---- phase 0: m0-3 x all n ----
    asm volatile("s_waitcnt vmcnt(2)" ::: "memory");  // B*,A0,A2 of cur landed
    __builtin_amdgcn_s_barrier();
    __builtin_amdgcn_sched_barrier(0);
#pragma unroll
    for (int m = 0; m < 4; ++m) {
      af[m] = *(const bf16x8*)(smem + aoff + abase0 + m * 2048);
      ag[m] = *(const bf16x8*)(smem + aoff + abase1 + m * 2048);
    }
#pragma unroll
    for (int n = 0; n < 3; ++n) {
      bfr[n] = *(const bf16x8*)(smem + 65536 + boff + bb0 + n * 2048);
      bgr[n] = *(const bf16x8*)(smem + 65536 + boff + bb1 + n * 2048);
    }
    // stage tile t+1 (pointers already advanced to t+1)
    gload16(pB0, smem + 65536 + bdst + wid * 1024);
    gload16(pB1, smem + 65536 + bdst + 8192 + wid * 1024);
    gload16(pB2, smem + 65536 + bdst + 16384 + wid * 1024);
    gload16(pA0, smem + adst + wid * 1024);
    gload16(pA2, smem + adst + 16384 + wid * 1024);
    __builtin_amdgcn_sched_barrier(0);
    __builtin_amdgcn_s_setprio(1);
#pragma unroll
    for (int m = 0; m < 4; ++m)
#pragma unroll
      for (int n = 0; n < 3; ++n) {
        acc[m][n] = __builtin_amdgcn_mfma_f32_16x16x32_bf16(af[m], bfr[n], acc[m][n], 0, 0, 0);
        acc[m][n] = __builtin_amdgcn_mfma_f32_16x16x32_bf16(ag[m], bgr[n], acc[m][n], 0, 0, 0);
      }
    __builtin_amdgcn_s_setprio(0);

    // ---- phase 1: m4-7 x all n ----
    asm volatile("s_waitcnt vmcnt(5)" ::: "memory");  // A1,A3 of cur landed
    __builtin_amdgcn_s_barrier();
    __builtin_amdgcn_sched_barrier(0);
#pragma unroll
    for (int m = 0; m < 4; ++m) {
      af[m] = *(const bf16x8*)(smem + aoff + abase0 + 8192 + m * 2048);
      ag[m] = *(const bf16x8*)(smem + aoff + abase1 + 8192 + m * 2048);
    }
    gload16(pA1, smem + adst + 8192 + wid * 1024);
    gload16(pA3, smem + adst + 24576 + wid * 1024);
    __builtin_amdgcn_sched_barrier(0);
    __builtin_amdgcn_s_setprio(1);
#pragma unroll
    for (int m = 0; m < 4; ++m)
#pragma unroll
      for (int n = 0; n < 3; ++n) {
        acc[4 + m][n] = __builtin_amdgcn_mfma_f32_16x16x32_bf16(af[m], bfr[n], acc[4 + m][n], 0, 0, 0);
        acc[4 + m][n] = __builtin_amdgcn_mfma_f32_16x16x32_bf16(ag[m], bgr[n], acc[4 + m][n], 0, 0, 0);
      }
    __builtin_amdgcn_s_setprio(0);

    pA0 += 128; pA1 += 128; pA2 += 128; pA3 += 128;
    pB0 += 128; pB1 += 128; pB2 += 128;
    aoff = adst; boff = bdst;
  }

  asm volatile("s_waitcnt vmcnt(0)" ::: "memory");  // drain tail stages
  __syncthreads();

  // ---- epilogue ----
  const int r0 = (lane >> 4) * 4;
  const int cl = lane & 15;
  if constexpr (EPI == 1) {
    float* Cwf = (float*)smem;   // reuse staging LDS: [256 rows][16 experts]
    {
      int row = tid >> 1, c8 = (tid & 1) * 8;
      const float* s = comb + (size_t)(rm0 + row) * N_EXP + c8;
      *(float4*)&Cwf[row * 16 + c8] = *(const float4*)s;
      *(float4*)&Cwf[row * 16 + c8 + 4] = *(const float4*)(s + 4);
    }
    __syncthreads();
#pragma unroll
    for (int n = 0; n < 3; ++n) {
      int colg = cn0 + wc * 48 + n * 16 + cl;
      int e = (colg < 4096) ? (colg >> 9) : (8 + ((colg - 4096) >> 10));
#pragma unroll
      for (int m = 0; m < 8; ++m) {
        int rl = wr * 128 + m * 16 + r0;
#pragma unroll
        for (int r = 0; r < 4; ++r) {
          float v = gelu_f(acc[m][n][r]) * Cwf[(rl + r) * 16 + e];
          hout[(size_t)(rm0 + rl + r) * W_TOT + colg] = f2bf(v);
        }
      }
    }
  } else {
    float* pz = pout + (size_t)zt * T_TOK * D_EMB;
#pragma unroll
    for (int n = 0; n < 3; ++n) {
      int colg = cn0 + wc * 48 + n * 16 + cl;
#pragma unroll
      for (int m = 0; m < 8; ++m) {
        int rl = wr * 128 + m * 16 + r0;
#pragma unroll
        for (int r = 0; r < 4; ++r)
          pz[(size_t)(rm0 + rl + r) * D_EMB + colg] = acc[m][n][r];
      }
    }
  }
}

__global__ __launch_bounds__(256) void reduce_kernel(
    const float* __restrict__ partial, float* __restrict__ out, int splits) {
  int i = (blockIdx.x * 256 + threadIdx.x) * 4;
  if (i >= T_TOK * D_EMB) return;
  float4 s = *(const float4*)(partial + i);
  for (int sp = 1; sp < splits; ++sp) {
    float4 v = *(const float4*)(partial + (size_t)sp * T_TOK * D_EMB + i);
    s.x += v.x; s.y += v.y; s.z += v.z; s.w += v.w;
  }
  *(float4*)(out + i) = s;
}

// ---------------- launcher ----------------

extern "C" void kernel_launch(void* const* d_in, const int* in_sizes, int n_in,
                              void* d_out, int out_size, void* d_ws, size_t ws_size,
                              hipStream_t stream) {
  const float* x = (const float*)d_in[0];
  const float* router_w = (const float*)d_in[1];
  const float* w1 = (const float*)d_in[2];
  const float* w2 = (const float*)d_in[3];
  float* out = (float*)d_out;

  char* ws = (char*)d_ws;
  size_t off = 0;
  auto alloc = [&](size_t bytes) {
    char* p = ws + off;
    off += (bytes + 255) & ~(size_t)255;
    return p;
  };
  unsigned short* xb  = (unsigned short*)alloc((size_t)T_TOK * D_EMB * 2);
  unsigned short* w1t = (unsigned short*)alloc((size_t)W_TOT * D_EMB * 2);
  unsigned short* w2t = (unsigned short*)alloc((size_t)D_EMB * W_TOT * 2);
  unsigned short* h   = (unsigned short*)alloc((size_t)T_TOK * W_TOT * 2);
  float* comb         = (float*)alloc((size_t)T_TOK * N_EXP * 4);

  // split-K for GEMM2: prefer 16 (XCD split-pair map, L2-fit chunks)
  int splits = 16;
  if (off + (size_t)16 * T_TOK * D_EMB * 4 > ws_size) splits = 8;
  if (off + (size_t)8 * T_TOK * D_EMB * 4 > ws_size) splits = 4;
  float* partial = (float*)alloc((size_t)splits * T_TOK * D_EMB * 4);
  int kchunk = W_TOT / splits;

  transpose_cvt_kernel<<<dim3(W_TOT / 32, D_EMB / 32), 256, 0, stream>>>(w1, w1t, D_EMB, W_TOT);
  transpose_cvt_kernel<<<dim3(D_EMB / 32, W_TOT / 32), 256, 0, stream>>>(w2, w2t, W_TOT, D_EMB);
  router_kernel<<<T_TOK / 4, 256, 0, stream>>>(x, router_w, comb, xb);

  // GEMM1: H = gelu(X W1) * comb ; grid 512: XCD = mt (bid&7), nt = bid>>3
  gemm_kernel<1, 0><<<512, 512, 0, stream>>>(
      xb, w1t, D_EMB, D_EMB, D_EMB / 64, D_EMB, 1, comb, h, nullptr);

  // GEMM2: OUT = H W2
  if (splits >= 8) {
    // grid 32*splits: XCD owns split-pair {x, x+8}; exact 1-2 rounds
    gemm_kernel<0, 1><<<32 * splits, 512, 0, stream>>>(
        h, w2t, W_TOT, W_TOT, kchunk / 64, kchunk, splits, nullptr, nullptr, partial);
  } else {
    gemm_kernel<0, 2><<<32 * splits, 512, 0, stream>>>(
        h, w2t, W_TOT, W_TOT, kchunk / 64, kchunk, splits, nullptr, nullptr, partial);
  }
  reduce_kernel<<<(T_TOK * D_EMB) / 1024, 256, 0, stream>>>(partial, out, splits);
}